// Round 1
// baseline (59565.173 us; speedup 1.0000x reference)
//
#include <hip/hip_runtime.h>
#include <math.h>

#define BB 64
#define TT 512
#define INS 512
#define HH 512
#define SS 3
#define LL 2
#define G3 1536
#define PEN 0.7f

// ---------------- prep: wsum (col-sums of Wlw), bsum, p/cur init, zero buffer ---------
__global__ void k_prep(const float* __restrict__ Wlw, const float* __restrict__ blw,
                       float* __restrict__ wsum, float* __restrict__ bsumb,
                       float* __restrict__ p, int* __restrict__ cur,
                       float* __restrict__ zerob) {
  int tid = blockIdx.x * blockDim.x + threadIdx.x;
  if (tid < HH) {
    float s = 0.f;
    for (int g = 0; g < HH; ++g) s += Wlw[g * HH + tid];
    wsum[tid] = s;
  }
  for (int i = tid; i < BB * HH; i += gridDim.x * blockDim.x) zerob[i] = 0.f;
  if (tid == 0) {
    float s = 0.f;
    for (int i = 0; i < HH; ++i) s += blw[i];
    *bsumb = s;
    p[0] = PEN; p[1] = 1.f; p[2] = 1.f;
    *cur = 0;
  }
}

// ---------------- xsum[t][i] = sum_b x[b][t][i] --------------------------------------
__global__ void k_xsum(const float* __restrict__ x, float* __restrict__ xsum) {
  int t = blockIdx.x;
  for (int ii = threadIdx.x; ii < INS; ii += 256) {
    float s = 0.f;
    const float* px = x + (size_t)t * INS + ii;
    for (int b = 0; b < BB; ++b) s += px[(size_t)b * TT * INS];
    xsum[(size_t)t * INS + ii] = s;
  }
}

// ---------------- router: computes cur (expert) and updates penalty p ----------------
__global__ void k_router(const float* __restrict__ h0, const float* __restrict__ h1,
                         const float* __restrict__ xsum_t,
                         const float* __restrict__ Wsel, const float* __restrict__ bsel,
                         const float* __restrict__ wsum, const float* __restrict__ bsumb,
                         float* __restrict__ p, int* __restrict__ cur) {
  __shared__ float red[256];
  __shared__ float le0[BB], le1[BB];
  __shared__ float lg[3];
  int tid = threadIdx.x;

  // Phase 1: le[l][b] = h[l][b][:] . wsum + bsum   (2 threads per (l,b) row)
  {
    int rowp = tid >> 1;
    int q = tid & 1;
    int l = rowp >> 6, b = rowp & 63;
    const float* hrow = (l == 0 ? h0 : h1) + (size_t)b * HH;
    float s = 0.f;
    int k0 = q * 256;
    for (int k = k0; k < k0 + 256; k += 4) {
      float4 hv = *(const float4*)(hrow + k);
      float4 wv = *(const float4*)(wsum + k);
      s += hv.x * wv.x + hv.y * wv.y + hv.z * wv.z + hv.w * wv.w;
    }
    red[tid] = s;
  }
  __syncthreads();
  if (tid < 128) {
    int l = tid >> 6, b = tid & 63;
    float v = red[2 * tid] + red[2 * tid + 1] + *bsumb;
    if (l == 0) le0[b] = v; else le1[b] = v;
  }
  __syncthreads();

  // Phase 2: shsum[h] = sum_b le0[b]*h0[b][h] + le1[b]*h1[b][h]; fold into logit partials
  float part0 = 0.f, part1 = 0.f, part2 = 0.f;
  for (int hh = tid; hh < HH; hh += 256) {
    float sh = 0.f;
    for (int b2 = 0; b2 < BB; ++b2) {
      sh += le0[b2] * h0[(size_t)b2 * HH + hh] + le1[b2] * h1[(size_t)b2 * HH + hh];
    }
    float xt = xsum_t[hh];
    part0 += sh * Wsel[0 * 1024 + hh] + xt * Wsel[0 * 1024 + 512 + hh];
    part1 += sh * Wsel[1 * 1024 + hh] + xt * Wsel[1 * 1024 + 512 + hh];
    part2 += sh * Wsel[2 * 1024 + hh] + xt * Wsel[2 * 1024 + 512 + hh];
  }
  for (int s = 0; s < 3; ++s) {
    float v = (s == 0) ? part0 : (s == 1) ? part1 : part2;
    __syncthreads();
    red[tid] = v;
    __syncthreads();
    for (int off = 128; off > 0; off >>= 1) {
      if (tid < off) red[tid] += red[tid + off];
      __syncthreads();
    }
    if (tid == 0) lg[s] = red[0];
  }
  __syncthreads();
  if (tid == 0) {
    float l0 = lg[0] + (float)BB * bsel[0];
    float l1 = lg[1] + (float)BB * bsel[1];
    float l2 = lg[2] + (float)BB * bsel[2];
    float m = fmaxf(l0, fmaxf(l1, l2));
    float e0 = expf(l0 - m), e1 = expf(l1 - m), e2 = expf(l2 - m);
    float Z = e0 + e1 + e2;
    float pr0 = e0 / Z * p[0], pr1 = e1 / Z * p[1], pr2 = e2 / Z * p[2];
    int c = 0; float best = pr0;
    if (pr1 > best) { best = pr1; c = 1; }
    if (pr2 > best) { best = pr2; c = 2; }
    *cur = c;
    float np0 = p[0] * (c == 0 ? PEN : 1.f);
    float np1 = p[1] * (c == 1 ? PEN : 1.f);
    float np2 = p[2] * (c == 2 ? PEN : 1.f);
    float mx = fmaxf(np0, fmaxf(np1, np2));
    p[0] = np0 / mx; p[1] = np1 / mx; p[2] = np2 / mx;
  }
}

// ---------------- fused GRU layer: gi = act@Wih^T, gh = hin@Whh^T, pointwise ---------
// block = 256 threads = 16 batch x 16 gate-k; grid = (32 ktiles, 4 btiles)
__global__ __launch_bounds__(256) void k_layer(
    const float* __restrict__ act, int act_stride,
    const float* __restrict__ hin,
    const float* __restrict__ WihAll, int wihExpStride,
    const float* __restrict__ WhhAll,
    const float* __restrict__ bihAll, const float* __restrict__ bhhAll,
    int layer, const int* __restrict__ curp,
    float* __restrict__ hout, float* __restrict__ hout2) {
  __shared__ float aT[INS][16];  // transposed: aT[k][b] -> conflict-free broadcast reads
  __shared__ float hT[HH][16];
  int cur = *curp;
  const float* Wih = WihAll + (size_t)cur * wihExpStride;
  const float* Whh = WhhAll + ((size_t)cur * LL + layer) * (size_t)(G3 * HH);
  const float* bih = bihAll + ((size_t)cur * LL + layer) * G3;
  const float* bhh = bhhAll + ((size_t)cur * LL + layer) * G3;
  int btile = blockIdx.y;
  int ktile = blockIdx.x;
  int tid = threadIdx.x;

  // stage 16 activation rows and 16 hidden rows into LDS (transposed)
  for (int f = tid; f < 16 * 128; f += 256) {
    int row = f >> 7, c4 = f & 127;
    int kb = c4 * 4;
    float4 va = *(const float4*)(act + (size_t)(btile * 16 + row) * act_stride + kb);
    aT[kb + 0][row] = va.x; aT[kb + 1][row] = va.y; aT[kb + 2][row] = va.z; aT[kb + 3][row] = va.w;
    float4 vh = *(const float4*)(hin + (size_t)(btile * 16 + row) * HH + kb);
    hT[kb + 0][row] = vh.x; hT[kb + 1][row] = vh.y; hT[kb + 2][row] = vh.z; hT[kb + 3][row] = vh.w;
  }
  __syncthreads();

  int tb = tid & 15, tk = tid >> 4;
  int k = ktile * 16 + tk;
  const float* wir = Wih + (size_t)k * INS;
  const float* wiz = Wih + (size_t)(k + HH) * INS;
  const float* win = Wih + (size_t)(k + 2 * HH) * INS;
  const float* whr = Whh + (size_t)k * HH;
  const float* whz = Whh + (size_t)(k + HH) * HH;
  const float* whn = Whh + (size_t)(k + 2 * HH) * HH;
  float air = 0.f, aiz = 0.f, ain = 0.f, ahr = 0.f, ahz = 0.f, ahn = 0.f;
#pragma unroll 4
  for (int c4 = 0; c4 < 128; ++c4) {
    int kb = c4 * 4;
    float4 w0 = *(const float4*)(wir + kb);
    float4 w1 = *(const float4*)(wiz + kb);
    float4 w2 = *(const float4*)(win + kb);
    float4 w3 = *(const float4*)(whr + kb);
    float4 w4 = *(const float4*)(whz + kb);
    float4 w5 = *(const float4*)(whn + kb);
    float a0 = aT[kb + 0][tb], a1 = aT[kb + 1][tb], a2 = aT[kb + 2][tb], a3 = aT[kb + 3][tb];
    float h0v = hT[kb + 0][tb], h1v = hT[kb + 1][tb], h2v = hT[kb + 2][tb], h3v = hT[kb + 3][tb];
    air += a0 * w0.x + a1 * w0.y + a2 * w0.z + a3 * w0.w;
    aiz += a0 * w1.x + a1 * w1.y + a2 * w1.z + a3 * w1.w;
    ain += a0 * w2.x + a1 * w2.y + a2 * w2.z + a3 * w2.w;
    ahr += h0v * w3.x + h1v * w3.y + h2v * w3.z + h3v * w3.w;
    ahz += h0v * w4.x + h1v * w4.y + h2v * w4.z + h3v * w4.w;
    ahn += h0v * w5.x + h1v * w5.y + h2v * w5.z + h3v * w5.w;
  }
  air += bih[k]; aiz += bih[k + HH]; ain += bih[k + 2 * HH];
  ahr += bhh[k]; ahz += bhh[k + HH]; ahn += bhh[k + 2 * HH];

  float r = 1.f / (1.f + expf(-(air + ahr)));
  float z = 1.f / (1.f + expf(-(aiz + ahz)));
  float n = tanhf(ain + r * ahn);
  int b = btile * 16 + tb;
  float hprev = hT[k][tb];
  float hv = (1.f - z) * n + z * hprev;
  hout[(size_t)b * HH + k] = hv;
  if (hout2) hout2[(size_t)b * HH + k] = hv;
}

extern "C" void kernel_launch(void* const* d_in, const int* in_sizes, int n_in,
                              void* d_out, int out_size, void* d_ws, size_t ws_size,
                              hipStream_t stream) {
  const float* x         = (const float*)d_in[0];
  const float* Wih_first = (const float*)d_in[1];
  const float* Wih_rest  = (const float*)d_in[2];
  const float* Whh       = (const float*)d_in[3];
  const float* bih       = (const float*)d_in[4];
  const float* bhh       = (const float*)d_in[5];
  const float* Wlw       = (const float*)d_in[6];
  const float* blw       = (const float*)d_in[7];
  const float* Wsel      = (const float*)d_in[8];
  const float* bsel      = (const float*)d_in[9];
  float* out = (float*)d_out;
  float* ws  = (float*)d_ws;

  float* h0a   = ws;
  float* h0b   = h0a + BB * HH;
  float* zerob = h0b + BB * HH;
  float* xsum  = zerob + BB * HH;
  float* wsum  = xsum + (size_t)TT * INS;
  float* bsumb = wsum + HH;
  float* p     = bsumb + 1;
  int*   cur   = (int*)(p + 3);

  k_prep<<<dim3(8), 256, 0, stream>>>(Wlw, blw, wsum, bsumb, p, cur, zerob);
  k_xsum<<<dim3(TT), 256, 0, stream>>>(x, xsum);

  for (int t = 0; t < TT; ++t) {
    const float* h0in = (t == 0) ? zerob : ((t & 1) ? h0a : h0b);
    float* h0out = (t & 1) ? h0b : h0a;
    const float* h1in = (t == 0) ? zerob : (out + (size_t)(t - 1) * BB * HH);
    if (t > 0) {
      k_router<<<1, 256, 0, stream>>>(h0in, h1in, xsum + (size_t)t * INS,
                                      Wsel, bsel, wsum, bsumb, p, cur);
    }
    // layer 0: act = x[:, t, :] (row stride T*IN)
    k_layer<<<dim3(32, 4), 256, 0, stream>>>(
        x + (size_t)t * INS, TT * INS, h0in,
        Wih_first, G3 * INS, Whh, bih, bhh, 0, cur, h0out, nullptr);
    // layer 1: act = h_new0 (contiguous), output goes straight to d_out row t
    float* o2 = (t == TT - 1) ? (out + (size_t)TT * BB * HH) : nullptr;
    k_layer<<<dim3(32, 4), 256, 0, stream>>>(
        h0out, HH, h1in,
        Wih_rest, G3 * HH, Whh, bih, bhh, 1, cur,
        out + (size_t)t * BB * HH, o2);
  }
}

// Round 2
// 56551.343 us; speedup vs baseline: 1.0533x; 1.0533x over previous
//
#include <hip/hip_runtime.h>
#include <math.h>

#define BB 64
#define TT 512
#define HH 512
#define KK 512
#define G3 1536
#define PEN 0.7f
#define NBLK 256
#define WSTRIDE ((size_t)(G3 * KK))

// ---------------------------------------------------------------------------
// grid barrier: monotonic counter; release on arrival, relaxed spin (no cache
// invalidate per poll), single acquire on exit.
__device__ __forceinline__ void gbar(unsigned* cnt, unsigned target) {
  __syncthreads();
  if (threadIdx.x == 0) {
    __hip_atomic_fetch_add(cnt, 1u, __ATOMIC_RELEASE, __HIP_MEMORY_SCOPE_AGENT);
    while (__hip_atomic_load(cnt, __ATOMIC_RELAXED, __HIP_MEMORY_SCOPE_AGENT) < target)
      __builtin_amdgcn_s_sleep(2);
    (void)__hip_atomic_load(cnt, __ATOMIC_ACQUIRE, __HIP_MEMORY_SCOPE_AGENT);
  }
  __syncthreads();
}

// ---------------------------------------------------------------------------
// pre 1: xc[t][s] = sum_b x[b,t,:] . Wsel[s,512:] + B*bsel[s]
__global__ void k_pre_xc(const float* __restrict__ x, const float* __restrict__ Wsel,
                         const float* __restrict__ bsel, float* __restrict__ xc) {
  int t = blockIdx.x, tid = threadIdx.x;
  __shared__ float xs[512];
  __shared__ float a0[256], a1[256], a2[256];
  for (int i = tid; i < 512; i += 256) {
    float s = 0.f;
    const float* px = x + (size_t)t * KK + i;
    for (int b = 0; b < BB; ++b) s += px[(size_t)b * TT * KK];
    xs[i] = s;
  }
  __syncthreads();
  float c0 = 0.f, c1 = 0.f, c2 = 0.f;
  for (int i = tid; i < 512; i += 256) {
    float v = xs[i];
    c0 += v * Wsel[512 + i];
    c1 += v * Wsel[1024 + 512 + i];
    c2 += v * Wsel[2048 + 512 + i];
  }
  a0[tid] = c0; a1[tid] = c1; a2[tid] = c2;
  __syncthreads();
  for (int off = 128; off; off >>= 1) {
    if (tid < off) { a0[tid] += a0[tid + off]; a1[tid] += a1[tid + off]; a2[tid] += a2[tid + off]; }
    __syncthreads();
  }
  if (tid == 0) {
    xc[t * 4 + 0] = a0[0] + 64.f * bsel[0];
    xc[t * 4 + 1] = a1[0] + 64.f * bsel[1];
    xc[t * 4 + 2] = a2[0] + 64.f * bsel[2];
  }
}

// pre 2: wsum (col-sums of Wlw), bsum, counter=0
__global__ void k_pre_misc(const float* __restrict__ Wlw, const float* __restrict__ blw,
                           float* __restrict__ wsum, float* __restrict__ bsumb,
                           unsigned* __restrict__ cnt) {
  int tid = threadIdx.x;
  for (int h = tid; h < 512; h += 256) {
    float s = 0.f;
    for (int g = 0; g < 512; ++g) s += Wlw[(size_t)g * 512 + h];
    wsum[h] = s;
  }
  __shared__ float red[256];
  float s = 0.f;
  for (int i = tid; i < 512; i += 256) s += blw[i];
  red[tid] = s;
  __syncthreads();
  for (int off = 128; off; off >>= 1) {
    if (tid < off) red[tid] += red[tid + off];
    __syncthreads();
  }
  if (tid == 0) { *bsumb = red[0]; *cnt = 0u; }
}

// ---------------------------------------------------------------------------
// one GRU layer for this block's 8 j x 16 b outputs.
// LDS: als/hls hold 16 rows x 512 floats, XOR-swizzled at float4 granularity
// (phys_c = c ^ (row&7)) so the 32 distinct 16B reads per wave hit the LDS
// bandwidth floor instead of a same-bank 8x serialization.
__device__ __forceinline__ void do_layer(
    float* __restrict__ smem, int tid, int jt, int bt, int zeroH,
    const float* __restrict__ actbase, size_t actStride,
    const float* __restrict__ hbase,
    const float* __restrict__ Wih, const float* __restrict__ Whh,
    const float* __restrict__ bihL, const float* __restrict__ bhhL,
    float* __restrict__ hout, float* __restrict__ hout2) {
  float* als = smem;
  float* hls = smem + 8192;
#pragma unroll
  for (int ff = 0; ff < 8; ++ff) {
    int f = tid + ff * 256;
    int row = f >> 7, c = f & 127;
    int ph = (row << 9) + ((c ^ (row & 7)) << 2);
    float4 av = *(const float4*)(actbase + (size_t)(bt * 16 + row) * actStride + (c << 2));
    *(float4*)(als + ph) = av;
    float4 hv = make_float4(0.f, 0.f, 0.f, 0.f);
    if (!zeroH) hv = *(const float4*)(hbase + (size_t)(bt * 16 + row) * HH + (c << 2));
    *(float4*)(hls + ph) = hv;
  }
  __syncthreads();
  int half = tid & 1, bl = (tid >> 1) & 15, jl = tid >> 5;
  int j = (jt << 3) + jl;
  int r = bl & 7;
  const float* wir = Wih + (size_t)j * KK + half * 256;
  const float* wiz = wir + (size_t)HH * KK;
  const float* win = wiz + (size_t)HH * KK;
  const float* whr = Whh + (size_t)j * KK + half * 256;
  const float* whz = whr + (size_t)HH * KK;
  const float* whn = whz + (size_t)HH * KK;
  const float* ap = als + (bl << 9) + half * 256;
  const float* hpp = hls + (bl << 9) + half * 256;
  float air = 0.f, aiz = 0.f, ain = 0.f, ahr = 0.f, ahz = 0.f, ahn = 0.f;
#pragma unroll 4
  for (int pc = 0; pc < 64; ++pc) {
    int kx = (pc ^ r) << 2;  // logical k chunk for this physical LDS slot
    float4 a4 = *(const float4*)(ap + (pc << 2));
    float4 h4 = *(const float4*)(hpp + (pc << 2));
    float4 w0 = *(const float4*)(wir + kx);
    float4 w1 = *(const float4*)(wiz + kx);
    float4 w2 = *(const float4*)(win + kx);
    float4 w3 = *(const float4*)(whr + kx);
    float4 w4 = *(const float4*)(whz + kx);
    float4 w5 = *(const float4*)(whn + kx);
    air += a4.x * w0.x + a4.y * w0.y + a4.z * w0.z + a4.w * w0.w;
    aiz += a4.x * w1.x + a4.y * w1.y + a4.z * w1.z + a4.w * w1.w;
    ain += a4.x * w2.x + a4.y * w2.y + a4.z * w2.z + a4.w * w2.w;
    ahr += h4.x * w3.x + h4.y * w3.y + h4.z * w3.z + h4.w * w3.w;
    ahz += h4.x * w4.x + h4.y * w4.y + h4.z * w4.z + h4.w * w4.w;
    ahn += h4.x * w5.x + h4.y * w5.y + h4.z * w5.z + h4.w * w5.w;
  }
  air += __shfl_xor(air, 1);
  aiz += __shfl_xor(aiz, 1);
  ain += __shfl_xor(ain, 1);
  ahr += __shfl_xor(ahr, 1);
  ahz += __shfl_xor(ahz, 1);
  ahn += __shfl_xor(ahn, 1);
  if (half == 0) {
    float rg = 1.f / (1.f + expf(-(air + bihL[j] + ahr + bhhL[j])));
    float zg = 1.f / (1.f + expf(-(aiz + bihL[j + 512] + ahz + bhhL[j + 512])));
    float ng = tanhf(ain + bihL[j + 1024] + rg * (ahn + bhhL[j + 1024]));
    float hprev = zeroH ? 0.f : hls[(bl << 9) + (((j >> 2) ^ r) << 2) + (j & 3)];
    float hv = (1.f - zg) * ng + zg * hprev;
    size_t oi = (size_t)(bt * 16 + bl) * HH + j;
    hout[oi] = hv;
    if (hout2) hout2[oi] = hv;
  }
}

// ---------------------------------------------------------------------------
__global__ __launch_bounds__(256, 1) void k_persist(
    const float* __restrict__ x,
    const float* __restrict__ Wih_first, const float* __restrict__ Wih_rest,
    const float* __restrict__ Whh,
    const float* __restrict__ bih, const float* __restrict__ bhh,
    const float* __restrict__ Wsel,
    const float* __restrict__ wsum, const float* __restrict__ bsumb,
    const float* __restrict__ xc,
    float* __restrict__ h0a, float* __restrict__ h0b,
    float* __restrict__ out, unsigned* __restrict__ cnt) {
  __shared__ float smem[16384];  // 64 KB: act tile + h tile (router partials aliased)
  int tid = threadIdx.x, bid = blockIdx.x;
  int jt = bid & 63, bt = bid >> 6;
  float p0 = PEN, p1 = 1.f, p2 = 1.f;  // penalty state, replicated per block
  int cur = 0;
  unsigned nbar = 0;
  float bs = *bsumb;

  for (int t = 0; t < TT; ++t) {
    float* hw = (t & 1) ? h0b : h0a;
    const float* hp = (t & 1) ? h0a : h0b;

    if (t > 0) {
      // ---- router, computed redundantly by every block (identical code+data
      // -> identical cur/p on all blocks; saves a grid barrier) ----
      int half = tid & 1;
      int rowp = tid >> 1;
      int l = rowp >> 6, bb = rowp & 63;
      const float* hrow = (l ? (out + (size_t)(t - 1) * BB * HH) : hp)
                          + (size_t)bb * HH + half * 256;
      const float* wsv = wsum + half * 256;
      const float* se0 = Wsel + half * 256;
      const float* se1 = Wsel + 1024 + half * 256;
      const float* se2 = Wsel + 2048 + half * 256;
      float d = 0.f, e0 = 0.f, e1 = 0.f, e2 = 0.f;
#pragma unroll 4
      for (int c = 0; c < 64; ++c) {
        float4 h4 = *(const float4*)(hrow + (c << 2));
        float4 w4 = *(const float4*)(wsv + (c << 2));
        float4 s0 = *(const float4*)(se0 + (c << 2));
        float4 s1 = *(const float4*)(se1 + (c << 2));
        float4 s2 = *(const float4*)(se2 + (c << 2));
        d  += h4.x * w4.x + h4.y * w4.y + h4.z * w4.z + h4.w * w4.w;
        e0 += h4.x * s0.x + h4.y * s0.y + h4.z * s0.z + h4.w * s0.w;
        e1 += h4.x * s1.x + h4.y * s1.y + h4.z * s1.z + h4.w * s1.w;
        e2 += h4.x * s2.x + h4.y * s2.y + h4.z * s2.z + h4.w * s2.w;
      }
      d  += __shfl_xor(d, 1);
      e0 += __shfl_xor(e0, 1);
      e1 += __shfl_xor(e1, 1);
      e2 += __shfl_xor(e2, 1);
      float le = d + bs;
      float v0 = le * e0, v1 = le * e1, v2 = le * e2;
      // butterfly over row bits (1..5); pair lanes hold identical values so
      // this sums each of the wave's 32 rows exactly once.
#pragma unroll
      for (int off = 2; off < 64; off <<= 1) {
        v0 += __shfl_xor(v0, off);
        v1 += __shfl_xor(v1, off);
        v2 += __shfl_xor(v2, off);
      }
      int wid = tid >> 6;
      if ((tid & 63) == 0) { smem[wid * 3 + 0] = v0; smem[wid * 3 + 1] = v1; smem[wid * 3 + 2] = v2; }
      __syncthreads();
      float l0 = smem[0] + smem[3] + smem[6] + smem[9]  + xc[t * 4 + 0];
      float l1 = smem[1] + smem[4] + smem[7] + smem[10] + xc[t * 4 + 1];
      float l2 = smem[2] + smem[5] + smem[8] + smem[11] + xc[t * 4 + 2];
      __syncthreads();  // release smem before layer staging reuses it
      float m = fmaxf(l0, fmaxf(l1, l2));
      float q0 = expf(l0 - m), q1 = expf(l1 - m), q2 = expf(l2 - m);
      float Z = q0 + q1 + q2;
      float pr0 = q0 / Z * p0, pr1 = q1 / Z * p1, pr2 = q2 / Z * p2;
      cur = 0;
      float best = pr0;
      if (pr1 > best) { best = pr1; cur = 1; }
      if (pr2 > best) { best = pr2; cur = 2; }
      p0 *= (cur == 0) ? PEN : 1.f;
      p1 *= (cur == 1) ? PEN : 1.f;
      p2 *= (cur == 2) ? PEN : 1.f;
      float mx = fmaxf(p0, fmaxf(p1, p2));
      p0 /= mx; p1 /= mx; p2 /= mx;
    }

    // ---- layer 0 ----
    const float* Wih0 = Wih_first + (size_t)cur * WSTRIDE;
    const float* Whh0 = Whh + (size_t)(cur * 2 + 0) * WSTRIDE;
    const float* bih0 = bih + (size_t)(cur * 2 + 0) * G3;
    const float* bhh0 = bhh + (size_t)(cur * 2 + 0) * G3;
    do_layer(smem, tid, jt, bt, (t == 0), x + (size_t)t * KK, (size_t)TT * KK,
             hp, Wih0, Whh0, bih0, bhh0, hw, nullptr);
    gbar(cnt, (++nbar) * NBLK);

    // ---- layer 1 ----
    const float* Wih1 = Wih_rest + (size_t)cur * WSTRIDE;
    const float* Whh1 = Whh + (size_t)(cur * 2 + 1) * WSTRIDE;
    const float* bih1 = bih + (size_t)(cur * 2 + 1) * G3;
    const float* bhh1 = bhh + (size_t)(cur * 2 + 1) * G3;
    const float* h1p = (t == 0) ? nullptr : (out + (size_t)(t - 1) * BB * HH);
    float* o2 = (t == TT - 1) ? (out + (size_t)TT * BB * HH) : nullptr;
    do_layer(smem, tid, jt, bt, (t == 0), hw, (size_t)HH,
             h1p, Wih1, Whh1, bih1, bhh1, out + (size_t)t * BB * HH, o2);
    gbar(cnt, (++nbar) * NBLK);
  }
}

// ---------------------------------------------------------------------------
extern "C" void kernel_launch(void* const* d_in, const int* in_sizes, int n_in,
                              void* d_out, int out_size, void* d_ws, size_t ws_size,
                              hipStream_t stream) {
  const float* x         = (const float*)d_in[0];
  const float* Wih_first = (const float*)d_in[1];
  const float* Wih_rest  = (const float*)d_in[2];
  const float* Whh       = (const float*)d_in[3];
  const float* bih       = (const float*)d_in[4];
  const float* bhh       = (const float*)d_in[5];
  const float* Wlw       = (const float*)d_in[6];
  const float* blw       = (const float*)d_in[7];
  const float* Wsel      = (const float*)d_in[8];
  const float* bsel      = (const float*)d_in[9];
  float* out = (float*)d_out;
  float* ws  = (float*)d_ws;

  float* h0a   = ws;
  float* h0b   = h0a + BB * HH;
  float* xc    = h0b + BB * HH;      // 512*4
  float* wsum  = xc + TT * 4;
  float* bsumb = wsum + HH;
  unsigned* cnt = (unsigned*)(bsumb + 1);

  k_pre_xc<<<dim3(TT), 256, 0, stream>>>(x, Wsel, bsel, xc);
  k_pre_misc<<<dim3(1), 256, 0, stream>>>(Wlw, blw, wsum, bsumb, cnt);
  k_persist<<<dim3(NBLK), 256, 0, stream>>>(x, Wih_first, Wih_rest, Whh, bih, bhh,
                                            Wsel, wsum, bsumb, xc, h0a, h0b, out, cnt);
}